// Round 1
// baseline (447.467 us; speedup 1.0000x reference)
//
#include <hip/hip_runtime.h>

typedef __bf16 bhalf;
typedef __bf16 bhalf8 __attribute__((ext_vector_type(8)));
typedef __bf16 bhalf4 __attribute__((ext_vector_type(4)));
typedef float f32x4 __attribute__((ext_vector_type(4)));

#define T_SEQ 2048
#define HIDN  2048
#define NQH   32
#define NKVH  8
#define DH    64
#define NQKV  3072  // (NQ + 2*NKV) * D

// ---------------- elementwise cast fp32 -> bf16 ----------------
__global__ __launch_bounds__(256) void cast_bf16_k(const float* __restrict__ in,
                                                   bhalf* __restrict__ out, int n) {
  int i = (blockIdx.x * 256 + threadIdx.x) * 4;
  if (i + 3 < n) {
    float4 v = *(const float4*)(in + i);
    bhalf4 o;
    o[0] = (bhalf)v.x; o[1] = (bhalf)v.y; o[2] = (bhalf)v.z; o[3] = (bhalf)v.w;
    *(bhalf4*)(out + i) = o;
  }
}

// ---------------- transpose + cast: out[C][R] = (bf16) in[R][C] ----------------
__global__ __launch_bounds__(256) void transpose_cast_k(const float* __restrict__ in,
                                                        bhalf* __restrict__ out, int R, int C) {
  __shared__ float tile[32][33];
  int bx = blockIdx.x * 32;  // col base in `in`
  int by = blockIdx.y * 32;  // row base in `in`
  int tx = threadIdx.x & 31, ty = threadIdx.x >> 5;
#pragma unroll
  for (int p = 0; p < 4; ++p)
    tile[ty + 8 * p][tx] = in[(size_t)(by + ty + 8 * p) * C + bx + tx];
  __syncthreads();
#pragma unroll
  for (int p = 0; p < 4; ++p)
    out[(size_t)(bx + ty + 8 * p) * R + by + tx] = (bhalf)tile[tx][ty + 8 * p];
}

// ---------------- bf16 MFMA GEMM: C[M][N] = A[M][K] * Bt[N][K]^T ----------------
// 128x128 block tile, BK=32, 4 waves in 2x2, each wave 64x64 (4x4 of 16x16x32).
__global__ __launch_bounds__(256) void gemm_bf16_k(const bhalf* __restrict__ A,
                                                   const bhalf* __restrict__ Bt,
                                                   float* __restrict__ C, int M, int N, int K) {
  __shared__ __align__(16) bhalf As[128][40];
  __shared__ __align__(16) bhalf Bs[128][40];
  int tid = threadIdx.x, lane = tid & 63, wv = tid >> 6;
  int bm = blockIdx.y * 128, bn = blockIdx.x * 128;
  int wm = (wv >> 1) * 64, wn = (wv & 1) * 64;
  int m16 = lane & 15, q4 = lane >> 4;
  f32x4 zero4 = {0.f, 0.f, 0.f, 0.f};
  f32x4 acc[4][4];
#pragma unroll
  for (int mi = 0; mi < 4; ++mi)
#pragma unroll
    for (int ni = 0; ni < 4; ++ni) acc[mi][ni] = zero4;

  for (int k0 = 0; k0 < K; k0 += 32) {
#pragma unroll
    for (int c = 0; c < 2; ++c) {
      int gg = tid + c * 256;
      int row = gg >> 2, col = (gg & 3) * 8;
      *(bhalf8*)&As[row][col] = *(const bhalf8*)(A + (size_t)(bm + row) * K + k0 + col);
      *(bhalf8*)&Bs[row][col] = *(const bhalf8*)(Bt + (size_t)(bn + row) * K + k0 + col);
    }
    __syncthreads();
    bhalf8 af[4], bfr[4];
#pragma unroll
    for (int mi = 0; mi < 4; ++mi) af[mi] = *(const bhalf8*)&As[wm + mi * 16 + m16][q4 * 8];
#pragma unroll
    for (int ni = 0; ni < 4; ++ni) bfr[ni] = *(const bhalf8*)&Bs[wn + ni * 16 + m16][q4 * 8];
#pragma unroll
    for (int mi = 0; mi < 4; ++mi)
#pragma unroll
      for (int ni = 0; ni < 4; ++ni)
        acc[mi][ni] = __builtin_amdgcn_mfma_f32_16x16x32_bf16(af[mi], bfr[ni], acc[mi][ni], 0, 0, 0);
    __syncthreads();
  }
  // epilogue: C/D layout col = lane&15, row = (lane>>4)*4 + r
#pragma unroll
  for (int mi = 0; mi < 4; ++mi)
#pragma unroll
    for (int ni = 0; ni < 4; ++ni) {
      size_t base = (size_t)(bm + wm + mi * 16 + q4 * 4) * N + (bn + wn + ni * 16 + m16);
#pragma unroll
      for (int r = 0; r < 4; ++r) C[base + (size_t)r * N] = acc[mi][ni][r];
    }
}

// ---------------- fused RMSNorm + RoPE + split + cast ----------------
// one wave per (t, head) row of qkv fp32 (T x 3072); heads 0..31 -> q, 32..39 -> k, 40..47 -> v
__global__ __launch_bounds__(256) void normrope_k(const float* __restrict__ qkv,
                                                  const int* __restrict__ pos,
                                                  const float* __restrict__ qw,
                                                  const float* __restrict__ kw,
                                                  bhalf* __restrict__ qo,
                                                  bhalf* __restrict__ ko,
                                                  bhalf* __restrict__ vo) {
  int wid = blockIdx.x * 4 + (threadIdx.x >> 6);
  int lane = threadIdx.x & 63;
  int t = wid / 48, h = wid - t * 48;
  float x = qkv[(size_t)t * NQKV + h * 64 + lane];
  float o = x;
  if (h < 40) {
    float ss = x * x;
#pragma unroll
    for (int off = 32; off; off >>= 1) ss += __shfl_xor(ss, off);
    float y = x * rsqrtf(ss * (1.0f / 64.0f) + 1e-5f) * ((h < 32) ? qw[lane] : kw[lane]);
    int i = lane & 31;
    // inv_freq = theta^(-i/32) = 2^(-i * log2(1e6)/32)
    float freq = exp2f((float)i * -0.6228615177913804f);
    float ang = (float)pos[t] * freq;
    float c = cosf(ang), s = sinf(ang);
    float partner = __shfl_xor(y, 32);
    o = (lane < 32) ? (y * c - partner * s) : (y * c + partner * s);
  }
  if (h < 32)      qo[(size_t)t * 2048 + h * 64 + lane] = (bhalf)o;
  else if (h < 40) ko[(size_t)t * 512 + (h - 32) * 64 + lane] = (bhalf)o;
  else             vo[(size_t)t * 512 + (h - 40) * 64 + lane] = (bhalf)o;
}

// ---------------- flash attention (causal GQA) ----------------
// grid (T/64, NQ); 4 waves, wave w owns 16 q-rows; s-chunks of 32.
__global__ __launch_bounds__(256) void attn_k(const bhalf* __restrict__ q,
                                              const bhalf* __restrict__ k,
                                              const bhalf* __restrict__ v,
                                              bhalf* __restrict__ o) {
  __shared__ __align__(16) bhalf ks[32][72];      // (s, d) for K
  __shared__ __align__(16) bhalf vt[64][40];      // (d, s) transposed V
  __shared__ __align__(16) bhalf pb[4][16][40];   // per-wave P round-trip (t, s)
  int tid = threadIdx.x, lane = tid & 63, w = tid >> 6;
  int h = blockIdx.y, kh = h >> 2;
  int qb = blockIdx.x * 64;
  int m16 = lane & 15, q4 = lane >> 4;

  int trow = qb + w * 16 + m16;
  const bhalf* qp = q + (size_t)trow * 2048 + h * 64;
  bhalf8 qf0 = *(const bhalf8*)(qp + q4 * 8);        // A-frag: m=lane&15, k=quad*8+j
  bhalf8 qf1 = *(const bhalf8*)(qp + 32 + q4 * 8);

  f32x4 zero4 = {0.f, 0.f, 0.f, 0.f};
  f32x4 oacc[4];
  float mrun[4], lrun[4];
#pragma unroll
  for (int ni = 0; ni < 4; ++ni) oacc[ni] = zero4;
#pragma unroll
  for (int r = 0; r < 4; ++r) { mrun[r] = -1e30f; lrun[r] = 0.f; }

  int tmax = qb + w * 16 + 15;
  int nch = (qb + 64) >> 5;
  int srow = tid >> 3, sc8 = (tid & 7) * 8;
  for (int sc = 0; sc < nch; ++sc) {
    int s0 = sc * 32;
    {  // stage K chunk (s,d) and V chunk transposed (d,s)
      *(bhalf8*)&ks[srow][sc8] =
          *(const bhalf8*)(k + (size_t)(s0 + srow) * 512 + kh * 64 + sc8);
      bhalf8 vv = *(const bhalf8*)(v + (size_t)(s0 + srow) * 512 + kh * 64 + sc8);
#pragma unroll
      for (int j = 0; j < 8; ++j) vt[sc8 + j][srow] = vv[j];
    }
    __syncthreads();
    if (s0 <= tmax) {
      f32x4 sa[2];
#pragma unroll
      for (int st = 0; st < 2; ++st) {
        bhalf8 kf0 = *(const bhalf8*)&ks[st * 16 + m16][q4 * 8];
        bhalf8 kf1 = *(const bhalf8*)&ks[st * 16 + m16][32 + q4 * 8];
        f32x4 t0 = __builtin_amdgcn_mfma_f32_16x16x32_bf16(qf0, kf0, zero4, 0, 0, 0);
        sa[st] = __builtin_amdgcn_mfma_f32_16x16x32_bf16(qf1, kf1, t0, 0, 0, 0);
      }
#pragma unroll
      for (int r = 0; r < 4; ++r) {
        int tr = qb + w * 16 + q4 * 4 + r;
#pragma unroll
        for (int st = 0; st < 2; ++st) {
          int scol = s0 + st * 16 + m16;
          float xv = sa[st][r] * 0.125f;           // D^-0.5
          sa[st][r] = (scol > tr) ? -1e30f : xv;   // causal mask
        }
        float vm = fmaxf(sa[0][r], sa[1][r]);
        vm = fmaxf(vm, __shfl_xor(vm, 1));
        vm = fmaxf(vm, __shfl_xor(vm, 2));
        vm = fmaxf(vm, __shfl_xor(vm, 4));
        vm = fmaxf(vm, __shfl_xor(vm, 8));
        float mn = fmaxf(mrun[r], vm);
        float al = __expf(mrun[r] - mn);
        float ps = 0.f;
#pragma unroll
        for (int st = 0; st < 2; ++st) {
          float pe = __expf(sa[st][r] - mn);
          pb[w][q4 * 4 + r][st * 16 + m16] = (bhalf)pe;  // C-layout -> (t,s) in LDS
          ps += pe;
        }
        ps += __shfl_xor(ps, 1);
        ps += __shfl_xor(ps, 2);
        ps += __shfl_xor(ps, 4);
        ps += __shfl_xor(ps, 8);
        lrun[r] = lrun[r] * al + ps;
        mrun[r] = mn;
#pragma unroll
        for (int ni = 0; ni < 4; ++ni) oacc[ni][r] *= al;
      }
      // PV: A-frag of P from LDS, B-frag from transposed V
      bhalf8 ap = *(const bhalf8*)&pb[w][m16][q4 * 8];
#pragma unroll
      for (int ni = 0; ni < 4; ++ni) {
        bhalf8 bv = *(const bhalf8*)&vt[ni * 16 + m16][q4 * 8];
        oacc[ni] = __builtin_amdgcn_mfma_f32_16x16x32_bf16(ap, bv, oacc[ni], 0, 0, 0);
      }
    }
    __syncthreads();
  }
#pragma unroll
  for (int ni = 0; ni < 4; ++ni)
#pragma unroll
    for (int r = 0; r < 4; ++r) {
      int tr = qb + w * 16 + q4 * 4 + r;
      o[(size_t)tr * 2048 + h * 64 + ni * 16 + m16] = (bhalf)(oacc[ni][r] / lrun[r]);
    }
}

extern "C" void kernel_launch(void* const* d_in, const int* in_sizes, int n_in,
                              void* d_out, int out_size, void* d_ws, size_t ws_size,
                              hipStream_t stream) {
  const int* positions = (const int*)d_in[0];
  const float* hidden  = (const float*)d_in[1];
  const float* w_qkv   = (const float*)d_in[2];
  const float* w_out   = (const float*)d_in[3];
  const float* q_ln    = (const float*)d_in[4];
  const float* k_ln    = (const float*)d_in[5];
  float* out = (float*)d_out;

  char* wsp = (char*)d_ws;
  bhalf* hid_bf  = (bhalf*)(wsp);                 //  8,388,608 B
  bhalf* wqkvT   = (bhalf*)(wsp + 8388608);       // 12,582,912 B (3072 x 2048)
  bhalf* woutT   = (bhalf*)(wsp + 20971520);      //  8,388,608 B (2048 x 2048)
  float* qkv     = (float*)(wsp + 29360128);      // 25,165,824 B (2048 x 3072 fp32)
  bhalf* q_bf    = (bhalf*)(wsp + 54525952);      //  8,388,608 B
  bhalf* k_bf    = (bhalf*)(wsp + 62914560);      //  2,097,152 B
  bhalf* v_bf    = (bhalf*)(wsp + 65011712);      //  2,097,152 B
  bhalf* attn_bf = (bhalf*)(wsp + 29360128);      // aliases qkv (dead after normrope)

  cast_bf16_k<<<T_SEQ * HIDN / 1024, 256, 0, stream>>>(hidden, hid_bf, T_SEQ * HIDN);
  transpose_cast_k<<<dim3(NQKV / 32, HIDN / 32), 256, 0, stream>>>(w_qkv, wqkvT, HIDN, NQKV);
  transpose_cast_k<<<dim3(HIDN / 32, HIDN / 32), 256, 0, stream>>>(w_out, woutT, HIDN, HIDN);
  gemm_bf16_k<<<dim3(NQKV / 128, T_SEQ / 128), 256, 0, stream>>>(hid_bf, wqkvT, qkv,
                                                                 T_SEQ, NQKV, HIDN);
  normrope_k<<<T_SEQ * 48 / 4, 256, 0, stream>>>(qkv, positions, q_ln, k_ln, q_bf, k_bf, v_bf);
  attn_k<<<dim3(T_SEQ / 64, NQH), 256, 0, stream>>>(q_bf, k_bf, v_bf, attn_bf);
  gemm_bf16_k<<<dim3(HIDN / 128, T_SEQ / 128), 256, 0, stream>>>(attn_bf, woutT, out,
                                                                 T_SEQ, HIDN, HIDN);
}